// Round 1
// baseline (1073.417 us; speedup 1.0000x reference)
//
#include <hip/hip_runtime.h>

// ---------------------------------------------------------------------------
// HardwareOptimizedQuantumLLM  (B=4, S=1024, D=512, V=8192, SCALES={1,2,4,8,16}, WIN=8)
//
// Structure:
//   y1 = [cos(emb-cmean) | lc | msc | sem | 1] @ Wcat   (K=1056 bf16-MFMA GEMM)
//   where Wcat rows: [W_ctx@Wf3 | Wf4 | W_scale@Wf1 | W_sem@Wf2 | cvec | 0-pad]
//   then LN1+gelu, 3x residual (LN2 -> DxD GEMM -> +0.1*gelu), LN3 -> out.
//   tsim computed banded (|i-j|<=8) only, via symmetric dots of similarity rows.
// ---------------------------------------------------------------------------

#define DEV __device__ __forceinline__
typedef unsigned short u16;
typedef __bf16 bf16x8 __attribute__((ext_vector_type(8)));
typedef float f32x4 __attribute__((ext_vector_type(4)));

static constexpr int S = 1024;
static constexpr int D = 512;
static constexpr int KCAT = 1056;   // 512 ctx + 512 lc + 5 msc + 1 sem + 1 const + 25 pad

DEV u16 f2bf(float f) {            // fp32 -> bf16 (RNE)
  unsigned u = __float_as_uint(f);
  return (u16)((u + 0x7fffu + ((u >> 16) & 1u)) >> 16);
}
DEV float gelu(float x) { return 0.5f * x * (1.f + erff(x * 0.70710678118654752f)); }
DEV float wred(float v) {
#pragma unroll
  for (int off = 32; off; off >>= 1) v += __shfl_down(v, off, 64);
  return v;  // lane 0 holds the sum
}
DEV void bred2(float& a, float& b, float* sm, int tid) {  // 256-thread block reduce, 2 values
  a = wred(a); b = wred(b);
  int w = tid >> 6;
  if ((tid & 63) == 0) { sm[w] = a; sm[w + 4] = b; }
  __syncthreads();
  a = sm[0] + sm[1] + sm[2] + sm[3];
  b = sm[4] + sm[5] + sm[6] + sm[7];
  __syncthreads();
}

// ---------------- phases = tanh(emb) ----------------
__global__ __launch_bounds__(256) void k_phases(const float* __restrict__ emb,
                                                float* __restrict__ ph, int n4) {
  int idx = blockIdx.x * 256 + threadIdx.x, stride = gridDim.x * 256;
  for (; idx < n4; idx += stride) {
    float4 v = ((const float4*)emb)[idx];
    float4 o;
    o.x = tanhf(v.x); o.y = tanhf(v.y); o.z = tanhf(v.z); o.w = tanhf(v.w);
    ((float4*)ph)[idx] = o;
  }
}

// ---------------- context mean accumulation (grid: B*8) ----------------
__global__ __launch_bounds__(256) void k_cmean(const float* __restrict__ emb,
                                               const float* __restrict__ mask,
                                               float* __restrict__ cmacc) {
  int b = blockIdx.x >> 3, chunk = blockIdx.x & 7, tid = threadIdx.x;
  float a0 = 0.f, a1 = 0.f;
  for (int s = chunk * 128; s < chunk * 128 + 128; ++s) {
    float m = mask[b * S + s];
    const float* row = emb + (size_t)(b * S + s) * D;
    a0 += row[tid] * m; a1 += row[tid + 256] * m;
  }
  atomicAdd(cmacc + b * D + tid, a0);
  atomicAdd(cmacc + b * D + tid + 256, a1);
}

// ---------------- per-(b,i) similarity-row norms (one wave each) ----------------
__global__ __launch_bounds__(256) void k_norms(const float* __restrict__ sim,
                                               const int* __restrict__ tok,
                                               float* __restrict__ norms) {
  int wave = threadIdx.x >> 6, lane = threadIdx.x & 63;
  int idx = blockIdx.x * 4 + wave;
  const float4* rp = (const float4*)(sim + (size_t)tok[idx] * 8192);
  float acc = 0.f;
#pragma unroll 4
  for (int it = 0; it < 32; ++it) {
    float4 v = rp[lane + it * 64];
    acc += v.x * v.x + v.y * v.y + v.z * v.z + v.w * v.w;
  }
  acc = wred(acc);
  if (lane == 0) norms[idx] = fmaxf(sqrtf(acc), 1e-12f);
}

// ---------------- banded tsim: dots for o=1..8 (symmetry gives o<0) ----------------
__global__ __launch_bounds__(256) void k_dots(const float* __restrict__ sim,
                                              const int* __restrict__ tok,
                                              const float* __restrict__ norms,
                                              float* __restrict__ dots) {
  __shared__ float srow[8192];
  int idx = blockIdx.x, i = idx & 1023, tid = threadIdx.x;
  const float4* rp = (const float4*)(sim + (size_t)tok[idx] * 8192);
#pragma unroll
  for (int it = 0; it < 8; ++it) ((float4*)srow)[tid + it * 256] = rp[tid + it * 256];
  __syncthreads();
  int wave = tid >> 6, lane = tid & 63;
  float ni = norms[idx];
  for (int rep = 0; rep < 2; ++rep) {
    int o = 1 + wave + rep * 4;
    if (i + o < S) {
      const float4* qp = (const float4*)(sim + (size_t)tok[idx + o] * 8192);
      float acc = 0.f;
#pragma unroll 4
      for (int it = 0; it < 32; ++it) {
        float4 a = ((const float4*)srow)[lane + it * 64];
        float4 c = qp[lane + it * 64];
        acc += a.x * c.x + a.y * c.y + a.z * c.z + a.w * c.w;
      }
      acc = wred(acc);
      if (lane == 0) dots[(size_t)idx * 8 + o - 1] = acc / (ni * norms[idx + o]);
    }
  }
}

// ---------------- multi-scale coherence msc (one wave per (b,i)) ----------------
__global__ __launch_bounds__(256) void k_msc(const float* __restrict__ ph,
                                             float* __restrict__ msc) {
  int wave = threadIdx.x >> 6, lane = threadIdx.x & 63;
  int idx = blockIdx.x * 4 + wave, i = idx & 1023;
  const float* base = ph + (size_t)idx * D;
  int jmax = (S - 1 - i < 15) ? (S - 1 - i) : 15;
  float a0 = 0.f, a1 = 0.f, a2 = 0.f, a3 = 0.f, a4 = 0.f;
  for (int it = 0; it < 8; ++it) {
    int d = lane + it * 64;
    float sp = 0.f, sc = 0.f, ss = 0.f;
#pragma unroll
    for (int j = 0; j < 16; ++j) {
      float p = (j <= jmax) ? base[(size_t)j * D + d] : 0.f;
      sp += p; sc += __cosf(p); ss += __sinf(p);
      if (j == 0) a0 += __cosf(sp) * sc + __sinf(sp) * ss;
      else if (j == 1)  { float wm = sp * 0.5f;    a1 += __cosf(wm) * (sc * 0.5f)    + __sinf(wm) * (ss * 0.5f); }
      else if (j == 3)  { float wm = sp * 0.25f;   a2 += __cosf(wm) * (sc * 0.25f)   + __sinf(wm) * (ss * 0.25f); }
      else if (j == 7)  { float wm = sp * 0.125f;  a3 += __cosf(wm) * (sc * 0.125f)  + __sinf(wm) * (ss * 0.125f); }
      else if (j == 15) { float wm = sp * 0.0625f; a4 += __cosf(wm) * (sc * 0.0625f) + __sinf(wm) * (ss * 0.0625f); }
    }
  }
  a0 = wred(a0); a1 = wred(a1); a2 = wred(a2); a3 = wred(a3); a4 = wred(a4);
  if (lane == 0) {
    float* o = msc + (size_t)idx * 5;
    o[0] = a0 * (1.f / 512.f);
    o[1] = (jmax >= 1)  ? a1 * (1.f / 512.f) : 0.f;
    o[2] = (jmax >= 3)  ? a2 * (1.f / 512.f) : 0.f;
    o[3] = (jmax >= 7)  ? a3 * (1.f / 512.f) : 0.f;
    o[4] = (jmax >= 15) ? a4 * (1.f / 512.f) : 0.f;
  }
}

// ---------------- semantic coherence accumulation (one wave per (b,i)) ----------------
__global__ __launch_bounds__(256) void k_sem(const float* __restrict__ ph,
                                             const float* __restrict__ dots,
                                             float* __restrict__ semacc) {
  __shared__ float sw[4][17];
  int wave = threadIdx.x >> 6, lane = threadIdx.x & 63;
  int idx = blockIdx.x * 4 + wave, i = idx & 1023;
  if (lane < 17) {
    int o = lane - 8, j = i + o;
    float v = 0.f;
    if (j >= 0 && j < S) {
      if (o == 0) v = 1.f;
      else if (o > 0) v = dots[(size_t)idx * 8 + o - 1];
      else v = dots[(size_t)(idx + o) * 8 + (-o - 1)];
    }
    sw[wave][lane] = v;
  }
  __syncthreads();
  float swr[17];
#pragma unroll
  for (int o = 0; o < 17; ++o) swr[o] = sw[wave][o];
  int olo = (i < 8) ? 8 - i : 0;
  int ohi = (i > S - 9) ? (8 + (S - 1 - i)) : 16;
  const float* pbase = ph + (size_t)idx * D;
  float acc = 0.f;
  for (int it = 0; it < 8; ++it) {
    int d = lane + it * 64;
    float p0 = pbase[d];
    for (int oi = olo; oi <= ohi; ++oi) {
      float pj = ph[((size_t)idx + (oi - 8)) * D + d];
      acc += __cosf((p0 - pj) * swr[oi]);
    }
  }
  acc = wred(acc);
  if (lane == 0) atomicAdd(semacc + i, acc);
}

// ---------------- Wcat rows 0..511 = W_ctx @ Wf3 (grid: 2 x 32) ----------------
__global__ __launch_bounds__(256) void k_wcf(const float* __restrict__ wctx,
                                             const float* __restrict__ wfuse,
                                             float* __restrict__ wcat) {
  int n = (blockIdx.x & 1) * 256 + threadIdx.x;
  int kbase = (blockIdx.x >> 1) * 16;
  float acc[16] = {};
  for (int j = 0; j < 512; ++j) {
    float wf3 = wfuse[(size_t)(1024 + j) * 512 + n];
#pragma unroll
    for (int kk = 0; kk < 16; ++kk) acc[kk] += wctx[(size_t)(kbase + kk) * 512 + j] * wf3;
  }
#pragma unroll
  for (int kk = 0; kk < 16; ++kk) wcat[(size_t)(kbase + kk) * 512 + n] = acc[kk];
}

// ---------------- Wcat rows 1024..1055: Wsf, u, cvec, zero pad ----------------
__global__ __launch_bounds__(256) void k_wsmall(const float* __restrict__ Wsc,
    const float* __restrict__ Wsm, const float* __restrict__ bsc,
    const float* __restrict__ bsm, const float* __restrict__ bcx,
    const float* __restrict__ bfu, const float* __restrict__ Wf,
    float* __restrict__ wcat) {
  int n = blockIdx.x * 256 + threadIdx.x;
  float a0 = 0.f, a1 = 0.f, a2 = 0.f, a3 = 0.f, a4 = 0.f, au = 0.f, ac = 0.f;
  for (int j = 0; j < 512; ++j) {
    float wf1 = Wf[(size_t)j * 512 + n];
    float wf2 = Wf[(size_t)(512 + j) * 512 + n];
    float wf3 = Wf[(size_t)(1024 + j) * 512 + n];
    a0 += Wsc[j] * wf1; a1 += Wsc[512 + j] * wf1; a2 += Wsc[1024 + j] * wf1;
    a3 += Wsc[1536 + j] * wf1; a4 += Wsc[2048 + j] * wf1;
    au += Wsm[j] * wf2;
    ac += bsc[j] * wf1 + bsm[j] * wf2 + bcx[j] * wf3;
  }
  wcat[(size_t)1024 * 512 + n] = a0;
  wcat[(size_t)1025 * 512 + n] = a1;
  wcat[(size_t)1026 * 512 + n] = a2;
  wcat[(size_t)1027 * 512 + n] = a3;
  wcat[(size_t)1028 * 512 + n] = a4;
  wcat[(size_t)1029 * 512 + n] = au;
  wcat[(size_t)1030 * 512 + n] = ac + bfu[n];
  for (int k = 1031; k < 1056; ++k) wcat[(size_t)k * 512 + n] = 0.f;
}

// ---------------- build Xcat (bf16): [cos(emb-cmean) | lc | msc | sem | 1 | 0] ----------------
__global__ __launch_bounds__(256) void k_xcat(const float* __restrict__ emb,
    const float* __restrict__ cmacc, const float* __restrict__ msc,
    const float* __restrict__ semacc, u16* __restrict__ xcat) {
  int idx = blockIdx.x, b = idx >> 10, i = idx & 1023, tid = threadIdx.x;
  const float* erow = emb + (size_t)idx * D;
  u16* orow = xcat + (size_t)idx * KCAT;
  for (int c = tid; c < KCAT; c += 256) {
    float v;
    if (c < 512) {
      v = __cosf(erow[c] - cmacc[b * D + c] * (1.f / 1024.f));
    } else if (c < 1024) {
      int d = c - 512;
      v = (i < S - 1) ? __cosf(erow[D + d] - erow[d]) : 0.f;
    } else if (c < 1029) {
      v = msc[(size_t)idx * 5 + (c - 1024)];
    } else if (c == 1029) {
      int cnt = ((i < 8) ? i : 8) + ((S - 1 - i < 8) ? (S - 1 - i) : 8) + 1;
      v = semacc[i] / (4.f * (float)cnt * 512.f);
    } else if (c == 1030) {
      v = 1.f;
    } else v = 0.f;
    orow[c] = f2bf(v);
  }
}

// ---------------- bf16 MFMA GEMM: C[M,512] = A[M,K](bf16) @ B[K,512](fp32) + bias ----------------
// tile 64x128, block 256 (4 waves), BK=32, mfma_f32_16x16x32_bf16
__global__ __launch_bounds__(256) void k_gemm(const u16* __restrict__ A,
    const float* __restrict__ Bm, float* __restrict__ C,
    const float* __restrict__ bias, int K) {
  __shared__ __align__(16) u16 sA[64 * 40];    // [m][k], stride 40 (pad)
  __shared__ __align__(16) u16 sB[128 * 40];   // [n][k] transposed, stride 40
  int tid = threadIdx.x, wave = tid >> 6, lane = tid & 63;
  int m0 = blockIdx.x * 64, n0 = blockIdx.y * 128;
  int ar = tid >> 2, ako = (tid & 3) * 8;
  int bn = tid & 127, bkb = (tid >> 7) * 2;
  int q8 = (lane >> 4) * 8, l15 = lane & 15;
  f32x4 acc[8] = {};
  for (int k0 = 0; k0 < K; k0 += 32) {
    *(uint4*)&sA[ar * 40 + ako] = *(const uint4*)(A + (size_t)(m0 + ar) * K + k0 + ako);
#pragma unroll
    for (int it = 0; it < 8; ++it) {
      int k = bkb + it * 4;
      float f0 = Bm[(size_t)(k0 + k) * 512 + n0 + bn];
      float f1 = Bm[(size_t)(k0 + k + 1) * 512 + n0 + bn];
      unsigned pk = (unsigned)f2bf(f0) | ((unsigned)f2bf(f1) << 16);
      *(unsigned*)&sB[bn * 40 + k] = pk;
    }
    __syncthreads();
    bf16x8 af = *(const bf16x8*)&sA[(wave * 16 + l15) * 40 + q8];
#pragma unroll
    for (int f = 0; f < 8; ++f) {
      bf16x8 bfr = *(const bf16x8*)&sB[(f * 16 + l15) * 40 + q8];
      acc[f] = __builtin_amdgcn_mfma_f32_16x16x32_bf16(af, bfr, acc[f], 0, 0, 0);
    }
    __syncthreads();
  }
  int r0 = m0 + wave * 16 + (lane >> 4) * 4;
#pragma unroll
  for (int f = 0; f < 8; ++f) {
    int col = n0 + f * 16 + l15;
    float bv = bias ? bias[col] : 0.f;
#pragma unroll
    for (int r = 0; r < 4; ++r)
      C[(size_t)(r0 + r) * 512 + col] = acc[f][r] + bv;
  }
}

// ---------------- post-fuse: x = gelu(LN1(y1)); t = bf16(LN2(x)) ----------------
__global__ __launch_bounds__(256) void k_post_y1(const float* __restrict__ y,
    float* __restrict__ x, u16* __restrict__ t,
    const float* __restrict__ g1, const float* __restrict__ b1,
    const float* __restrict__ g2, const float* __restrict__ b2) {
  __shared__ float sm[8];
  int row = blockIdx.x, tid = threadIdx.x;
  size_t base = (size_t)row * 512;
  float v0 = y[base + tid], v1 = y[base + tid + 256];
  float s = v0 + v1, ss = v0 * v0 + v1 * v1;
  bred2(s, ss, sm, tid);
  float m = s * (1.f / 512.f);
  float inv = rsqrtf(ss * (1.f / 512.f) - m * m + 1e-5f);
  float x0 = gelu((v0 - m) * inv * g1[tid] + b1[tid]);
  float x1 = gelu((v1 - m) * inv * g1[tid + 256] + b1[tid + 256]);
  x[base + tid] = x0; x[base + tid + 256] = x1;
  s = x0 + x1; ss = x0 * x0 + x1 * x1;
  bred2(s, ss, sm, tid);
  m = s * (1.f / 512.f);
  inv = rsqrtf(ss * (1.f / 512.f) - m * m + 1e-5f);
  t[base + tid] = f2bf((x0 - m) * inv * g2[tid] + b2[tid]);
  t[base + tid + 256] = f2bf((x1 - m) * inv * g2[tid + 256] + b2[tid + 256]);
}

// ---------------- residual post: x += 0.1*gelu(h); then LN2->t (or LN3->out) ----------------
__global__ __launch_bounds__(256) void k_post_res(const float* __restrict__ h,
    float* __restrict__ x, u16* __restrict__ t, float* __restrict__ out,
    const float* __restrict__ g, const float* __restrict__ bb, int final_) {
  __shared__ float sm[8];
  int row = blockIdx.x, tid = threadIdx.x;
  size_t base = (size_t)row * 512;
  float x0 = x[base + tid] + 0.1f * gelu(h[base + tid]);
  float x1 = x[base + tid + 256] + 0.1f * gelu(h[base + tid + 256]);
  float s = x0 + x1, ss = x0 * x0 + x1 * x1;
  bred2(s, ss, sm, tid);
  float m = s * (1.f / 512.f);
  float inv = rsqrtf(ss * (1.f / 512.f) - m * m + 1e-5f);
  float n0 = (x0 - m) * inv * g[tid] + bb[tid];
  float n1 = (x1 - m) * inv * g[tid + 256] + bb[tid + 256];
  if (final_) {
    out[base + tid] = n0; out[base + tid + 256] = n1;
  } else {
    x[base + tid] = x0; x[base + tid + 256] = x1;
    t[base + tid] = f2bf(n0); t[base + tid + 256] = f2bf(n1);
  }
}

// ---------------------------------------------------------------------------
extern "C" void kernel_launch(void* const* d_in, const int* in_sizes, int n_in,
                              void* d_out, int out_size, void* d_ws, size_t ws_size,
                              hipStream_t stream) {
  const float* emb     = (const float*)d_in[0];
  const int*   tok     = (const int*)d_in[1];
  const float* mask    = (const float*)d_in[2];
  const float* sim     = (const float*)d_in[3];
  const float* W_scale = (const float*)d_in[4];
  const float* b_scale = (const float*)d_in[5];
  const float* W_sem   = (const float*)d_in[6];
  const float* b_sem   = (const float*)d_in[7];
  const float* W_ctx   = (const float*)d_in[8];
  const float* b_ctx   = (const float*)d_in[9];
  const float* W_fuse  = (const float*)d_in[10];
  const float* b_fuse  = (const float*)d_in[11];
  const float* ln1_g = (const float*)d_in[12], *ln1_b = (const float*)d_in[13];
  const float* ln2_g = (const float*)d_in[14], *ln2_b = (const float*)d_in[15];
  const float* ln3_g = (const float*)d_in[16], *ln3_b = (const float*)d_in[17];
  const float* W_e0 = (const float*)d_in[18], *b_e0 = (const float*)d_in[19];
  const float* W_e1 = (const float*)d_in[20], *b_e1 = (const float*)d_in[21];
  const float* W_e2 = (const float*)d_in[22], *b_e2 = (const float*)d_in[23];
  float* out = (float*)d_out;

  // workspace carve (all 256B aligned)
  char* w = (char*)d_ws; size_t off = 0;
  auto alloc = [&](size_t bytes) { void* p = w + off; off += (bytes + 255) & ~(size_t)255; return p; };
  float* phases = (float*)alloc((size_t)4096 * 512 * 4);   // tanh(emb)
  float* hbuf   = (float*)alloc((size_t)4096 * 512 * 4);   // y1 / h
  float* xbuf   = (float*)alloc((size_t)4096 * 512 * 4);   // residual state
  u16*   tbuf   = (u16*)  alloc((size_t)4096 * 512 * 2);   // LN2(x) bf16
  u16*   xcat   = (u16*)  alloc((size_t)4096 * KCAT * 2);  // fused GEMM input
  float* wcat   = (float*)alloc((size_t)KCAT * 512 * 4);   // fused weights
  float* msc    = (float*)alloc((size_t)4096 * 5 * 4);
  float* norms  = (float*)alloc((size_t)4096 * 4);
  float* dots   = (float*)alloc((size_t)4096 * 8 * 4);
  float* semacc = (float*)alloc((size_t)1024 * 4);         // contiguous with cmacc
  float* cmacc  = (float*)alloc((size_t)4 * 512 * 4);
  (void)ws_size; (void)in_sizes; (void)n_in; (void)out_size;

  hipMemsetAsync(semacc, 0, 1024 * 4 + 4 * 512 * 4, stream);

  k_phases<<<1024, 256, 0, stream>>>(emb, phases, 4096 * 512 / 4);
  k_cmean<<<32, 256, 0, stream>>>(emb, mask, cmacc);
  k_norms<<<1024, 256, 0, stream>>>(sim, tok, norms);
  k_msc<<<1024, 256, 0, stream>>>(phases, msc);
  k_dots<<<4096, 256, 0, stream>>>(sim, tok, norms, dots);
  k_sem<<<1024, 256, 0, stream>>>(phases, dots, semacc);

  k_wcf<<<64, 256, 0, stream>>>(W_ctx, W_fuse, wcat);
  k_wsmall<<<2, 256, 0, stream>>>(W_scale, W_sem, b_scale, b_sem, b_ctx, b_fuse, W_fuse, wcat);
  hipMemcpyAsync(wcat + (size_t)512 * 512, W_fuse + (size_t)1536 * 512,
                 (size_t)512 * 512 * 4, hipMemcpyDeviceToDevice, stream);

  k_xcat<<<4096, 256, 0, stream>>>(emb, cmacc, msc, semacc, xcat);
  k_gemm<<<dim3(64, 4), 256, 0, stream>>>(xcat, wcat, hbuf, nullptr, KCAT);
  k_post_y1<<<4096, 256, 0, stream>>>(hbuf, xbuf, tbuf, ln1_g, ln1_b, ln2_g, ln2_b);

  k_gemm<<<dim3(64, 4), 256, 0, stream>>>(tbuf, W_e0, hbuf, b_e0, 512);
  k_post_res<<<4096, 256, 0, stream>>>(hbuf, xbuf, tbuf, nullptr, ln2_g, ln2_b, 0);
  k_gemm<<<dim3(64, 4), 256, 0, stream>>>(tbuf, W_e1, hbuf, b_e1, 512);
  k_post_res<<<4096, 256, 0, stream>>>(hbuf, xbuf, tbuf, nullptr, ln2_g, ln2_b, 0);
  k_gemm<<<dim3(64, 4), 256, 0, stream>>>(tbuf, W_e2, hbuf, b_e2, 512);
  k_post_res<<<4096, 256, 0, stream>>>(hbuf, xbuf, nullptr, out, ln3_g, ln3_b, 1);
}

// Round 2
// 898.280 us; speedup vs baseline: 1.1950x; 1.1950x over previous
//
#include <hip/hip_runtime.h>

// ---------------------------------------------------------------------------
// HardwareOptimizedQuantumLLM  (B=4, S=1024, D=512, V=8192, SCALES={1,2,4,8,16}, WIN=8)
//
// R2: band-staged k_dots (fused norms, 150 MB demand vs 1.18 GB), scratch-free
// k_sem, bf16 [n][k] weight pre-transpose + 64x64-tile MFMA GEMMs (512 blocks).
// ---------------------------------------------------------------------------

#define DEV __device__ __forceinline__
typedef unsigned short u16;
typedef __bf16 bf16x8 __attribute__((ext_vector_type(8)));
typedef float f32x4 __attribute__((ext_vector_type(4)));

static constexpr int S = 1024;
static constexpr int D = 512;
static constexpr int KCAT = 1056;   // 512 ctx + 512 lc + 5 msc + 1 sem + 1 const + 25 pad

DEV u16 f2bf(float f) {            // fp32 -> bf16 (RNE)
  unsigned u = __float_as_uint(f);
  return (u16)((u + 0x7fffu + ((u >> 16) & 1u)) >> 16);
}
DEV float gelu(float x) { return 0.5f * x * (1.f + erff(x * 0.70710678118654752f)); }
DEV float wred(float v) {
#pragma unroll
  for (int off = 32; off; off >>= 1) v += __shfl_down(v, off, 64);
  return v;  // lane 0 holds the sum
}
DEV void bred2(float& a, float& b, float* sm, int tid) {  // 256-thread block reduce, 2 values
  a = wred(a); b = wred(b);
  int w = tid >> 6;
  if ((tid & 63) == 0) { sm[w] = a; sm[w + 4] = b; }
  __syncthreads();
  a = sm[0] + sm[1] + sm[2] + sm[3];
  b = sm[4] + sm[5] + sm[6] + sm[7];
  __syncthreads();
}

// ---------------- phases = tanh(emb) ----------------
__global__ __launch_bounds__(256) void k_phases(const float* __restrict__ emb,
                                                float* __restrict__ ph, int n4) {
  int idx = blockIdx.x * 256 + threadIdx.x, stride = gridDim.x * 256;
  for (; idx < n4; idx += stride) {
    float4 v = ((const float4*)emb)[idx];
    float4 o;
    o.x = tanhf(v.x); o.y = tanhf(v.y); o.z = tanhf(v.z); o.w = tanhf(v.w);
    ((float4*)ph)[idx] = o;
  }
}

// ---------------- context mean accumulation (grid: B*8) ----------------
__global__ __launch_bounds__(256) void k_cmean(const float* __restrict__ emb,
                                               const float* __restrict__ mask,
                                               float* __restrict__ cmacc) {
  int b = blockIdx.x >> 3, chunk = blockIdx.x & 7, tid = threadIdx.x;
  float a0 = 0.f, a1 = 0.f;
  for (int s = chunk * 128; s < chunk * 128 + 128; ++s) {
    float m = mask[b * S + s];
    const float* row = emb + (size_t)(b * S + s) * D;
    a0 += row[tid] * m; a1 += row[tid + 256] * m;
  }
  atomicAdd(cmacc + b * D + tid, a0);
  atomicAdd(cmacc + b * D + tid + 256, a1);
}

// ---------------- banded tsim + norms, chunk-parallel band staging ----------------
// grid.x = B*16 (64-anchor position groups), grid.y = 32 (256-float V chunks)
// LDS sT[c][row]: 256 x 76(pad, 72 rows used) fp32 = 76 KB -> 2 blocks/CU.
// lane = anchor: acc[o-1] += sT[c][lane]*sT[c][lane+o]; acc[8] = norm^2. No shuffles.
static constexpr int DP = 76;  // padded row-dim stride (12c+r banks: 8 groups -> 2-way, free)
__global__ __launch_bounds__(256) void k_dots(const float* __restrict__ sim,
                                              const int* __restrict__ tok,
                                              float* __restrict__ dots_raw,
                                              float* __restrict__ normsq) {
  __shared__ float sT[256 * DP];
  __shared__ int stok[72];
  int bx = blockIdx.x, cy = blockIdx.y, tid = threadIdx.x;
  int b = bx >> 4, g0 = (bx & 15) * 64;
  int gidx = b * S + g0;
  if (tid < 72) {
    int p = g0 + tid;
    stok[tid] = (p < S) ? tok[b * S + p] : -1;
  }
  __syncthreads();
  // load: thread t owns chunk-element c=t; iterates row-quads, writes b128 transposed
  int c = tid, cbase = cy * 256;
#pragma unroll 3
  for (int it = 0; it < 18; ++it) {
    float4 v;
#pragma unroll
    for (int j = 0; j < 4; ++j) {
      int tk = stok[it * 4 + j];
      ((float*)&v)[j] = (tk >= 0) ? sim[(size_t)tk * 8192 + cbase + c] : 0.f;
    }
    *(float4*)&sT[c * DP + it * 4] = v;
  }
  __syncthreads();
  int wave = tid >> 6, lane = tid & 63;
  float acc[9] = {};
#pragma unroll 2
  for (int cc = 0; cc < 64; ++cc) {
    const float* row = &sT[(wave * 64 + cc) * DP];
    float va = row[lane];
    acc[8] += va * va;
#pragma unroll
    for (int o = 1; o <= 8; ++o) acc[o - 1] += va * row[lane + o];
  }
  __syncthreads();            // done reading sT; reuse as reduction buffer
  float* red = sT;            // [wave][9][64]
#pragma unroll
  for (int s = 0; s < 9; ++s) red[(wave * 9 + s) * 64 + lane] = acc[s];
  __syncthreads();
  for (int u = tid; u < 576; u += 256) {
    int s = u >> 6, a = u & 63;
    float v = red[s * 64 + a] + red[(9 + s) * 64 + a] +
              red[(18 + s) * 64 + a] + red[(27 + s) * 64 + a];
    if (s < 8) atomicAdd(&dots_raw[(size_t)(gidx + a) * 8 + s], v);
    else       atomicAdd(&normsq[gidx + a], v);
  }
}

// ---------------- multi-scale coherence msc (one wave per (b,i)) ----------------
__global__ __launch_bounds__(256) void k_msc(const float* __restrict__ ph,
                                             float* __restrict__ msc) {
  int wave = threadIdx.x >> 6, lane = threadIdx.x & 63;
  int idx = blockIdx.x * 4 + wave, i = idx & 1023;
  const float* base = ph + (size_t)idx * D;
  int jmax = (S - 1 - i < 15) ? (S - 1 - i) : 15;
  float a0 = 0.f, a1 = 0.f, a2 = 0.f, a3 = 0.f, a4 = 0.f;
  for (int it = 0; it < 8; ++it) {
    int d = lane + it * 64;
    float sp = 0.f, sc = 0.f, ss = 0.f;
#pragma unroll
    for (int j = 0; j < 16; ++j) {
      float p = (j <= jmax) ? base[(size_t)j * D + d] : 0.f;
      sp += p; sc += __cosf(p); ss += __sinf(p);
      if (j == 0) a0 += __cosf(sp) * sc + __sinf(sp) * ss;
      else if (j == 1)  { float wm = sp * 0.5f;    a1 += __cosf(wm) * (sc * 0.5f)    + __sinf(wm) * (ss * 0.5f); }
      else if (j == 3)  { float wm = sp * 0.25f;   a2 += __cosf(wm) * (sc * 0.25f)   + __sinf(wm) * (ss * 0.25f); }
      else if (j == 7)  { float wm = sp * 0.125f;  a3 += __cosf(wm) * (sc * 0.125f)  + __sinf(wm) * (ss * 0.125f); }
      else if (j == 15) { float wm = sp * 0.0625f; a4 += __cosf(wm) * (sc * 0.0625f) + __sinf(wm) * (ss * 0.0625f); }
    }
  }
  a0 = wred(a0); a1 = wred(a1); a2 = wred(a2); a3 = wred(a3); a4 = wred(a4);
  if (lane == 0) {
    float* o = msc + (size_t)idx * 5;
    o[0] = a0 * (1.f / 512.f);
    o[1] = (jmax >= 1)  ? a1 * (1.f / 512.f) : 0.f;
    o[2] = (jmax >= 3)  ? a2 * (1.f / 512.f) : 0.f;
    o[3] = (jmax >= 7)  ? a3 * (1.f / 512.f) : 0.f;
    o[4] = (jmax >= 15) ? a4 * (1.f / 512.f) : 0.f;
  }
}

// ---------------- semantic coherence (one wave per (b,i)); scratch-free ----------------
__global__ __launch_bounds__(256) void k_sem(const float* __restrict__ ph,
                                             const float* __restrict__ dots_raw,
                                             const float* __restrict__ normsq,
                                             float* __restrict__ semacc) {
  __shared__ float sw[4][17];
  int wave = threadIdx.x >> 6, lane = threadIdx.x & 63;
  int idx = blockIdx.x * 4 + wave, i = idx & 1023;
  if (lane < 17) {
    int o = lane - 8, j = i + o;
    float v = 0.f;
    if (j >= 0 && j < S) {
      if (o == 0) v = 1.f;
      else {
        float dr = (o > 0) ? dots_raw[(size_t)idx * 8 + o - 1]
                           : dots_raw[(size_t)(idx + o) * 8 + (-o - 1)];
        float ni = fmaxf(sqrtf(normsq[idx]), 1e-12f);
        float nj = fmaxf(sqrtf(normsq[idx + o]), 1e-12f);
        v = dr / (ni * nj);
      }
    }
    sw[wave][lane] = v;
  }
  __syncthreads();
  const float* pbase = ph + (size_t)idx * D;
  float acc = 0.f;
  for (int it = 0; it < 8; ++it) {
    int d = lane + it * 64;
    float p0 = pbase[d];
#pragma unroll
    for (int oi = 0; oi < 17; ++oi) {      // compile-time bounds; sw read from LDS (broadcast)
      int o = oi - 8, j = i + o;
      bool valid = (j >= 0) && (j < S);
      int oc = valid ? o : 0;
      float pj = ph[(size_t)(idx + oc) * D + d];
      float sv = sw[wave][oi];
      acc += valid ? __cosf((p0 - pj) * sv) : 0.f;
    }
  }
  acc = wred(acc);
  if (lane == 0) atomicAdd(semacc + i, acc);
}

// ---------------- weight prep: fp32 [k][n] -> bf16 [n][k] (grid 8,8,4) ----------------
__global__ __launch_bounds__(256) void k_prep(const float* __restrict__ W0,
    const float* __restrict__ W1, const float* __restrict__ W2,
    const float* __restrict__ Wf, u16* __restrict__ T0, u16* __restrict__ T1,
    u16* __restrict__ T2, u16* __restrict__ wcatT) {
  __shared__ float tile[64][65];
  int z = blockIdx.z;
  const float* src = z == 0 ? W0 : z == 1 ? W1 : z == 2 ? W2 : Wf + (size_t)1536 * 512;
  int r0 = blockIdx.y * 64, c0 = blockIdx.x * 64;
  int tr = threadIdx.x >> 6, tc = threadIdx.x & 63;
#pragma unroll 4
  for (int i = 0; i < 16; ++i)
    tile[tr + i * 4][tc] = src[(size_t)(r0 + tr + i * 4) * 512 + c0 + tc];
  __syncthreads();
#pragma unroll 4
  for (int i = 0; i < 16; ++i) {
    int n = c0 + tr + i * 4, k = r0 + tc;
    u16 v = f2bf(tile[tc][tr + i * 4]);
    if (z == 3) wcatT[(size_t)n * KCAT + 512 + k] = v;
    else (z == 0 ? T0 : z == 1 ? T1 : T2)[(size_t)n * 512 + k] = v;
  }
}

// ---------------- wcatT rows k=0..511 = (W_ctx @ Wf3)^T bf16 (grid: 2 x 32) ----------------
__global__ __launch_bounds__(256) void k_wcf(const float* __restrict__ wctx,
                                             const float* __restrict__ wfuse,
                                             u16* __restrict__ wcatT) {
  int n = (blockIdx.x & 1) * 256 + threadIdx.x;
  int kbase = (blockIdx.x >> 1) * 16;
  float acc[16] = {};
  for (int j = 0; j < 512; ++j) {
    float wf3 = wfuse[(size_t)(1024 + j) * 512 + n];
#pragma unroll
    for (int kk = 0; kk < 16; ++kk) acc[kk] += wctx[(size_t)(kbase + kk) * 512 + j] * wf3;
  }
#pragma unroll
  for (int kk = 0; kk < 16; ++kk) wcatT[(size_t)n * KCAT + kbase + kk] = f2bf(acc[kk]);
}

// ---------------- wcatT k=1024..1055: rank-5/rank-1/const folds + pad ----------------
__global__ __launch_bounds__(256) void k_wsmall(const float* __restrict__ Wsc,
    const float* __restrict__ Wsm, const float* __restrict__ bsc,
    const float* __restrict__ bsm, const float* __restrict__ bcx,
    const float* __restrict__ bfu, const float* __restrict__ Wf,
    u16* __restrict__ wcatT) {
  int n = blockIdx.x * 256 + threadIdx.x;
  float a0 = 0.f, a1 = 0.f, a2 = 0.f, a3 = 0.f, a4 = 0.f, au = 0.f, ac = 0.f;
  for (int j = 0; j < 512; ++j) {
    float wf1 = Wf[(size_t)j * 512 + n];
    float wf2 = Wf[(size_t)(512 + j) * 512 + n];
    float wf3 = Wf[(size_t)(1024 + j) * 512 + n];
    a0 += Wsc[j] * wf1; a1 += Wsc[512 + j] * wf1; a2 += Wsc[1024 + j] * wf1;
    a3 += Wsc[1536 + j] * wf1; a4 += Wsc[2048 + j] * wf1;
    au += Wsm[j] * wf2;
    ac += bsc[j] * wf1 + bsm[j] * wf2 + bcx[j] * wf3;
  }
  u16* row = wcatT + (size_t)n * KCAT;
  row[1024] = f2bf(a0); row[1025] = f2bf(a1); row[1026] = f2bf(a2);
  row[1027] = f2bf(a3); row[1028] = f2bf(a4); row[1029] = f2bf(au);
  row[1030] = f2bf(ac + bfu[n]);
  for (int k = 1031; k < KCAT; ++k) row[k] = 0;
}

// ---------------- build Xcat (bf16): [cos(emb-cmean) | lc | msc | sem | 1 | 0] ----------------
__global__ __launch_bounds__(256) void k_xcat(const float* __restrict__ emb,
    const float* __restrict__ cmacc, const float* __restrict__ msc,
    const float* __restrict__ semacc, u16* __restrict__ xcat) {
  int idx = blockIdx.x, b = idx >> 10, i = idx & 1023, tid = threadIdx.x;
  const float* erow = emb + (size_t)idx * D;
  u16* orow = xcat + (size_t)idx * KCAT;
  for (int c = tid; c < KCAT; c += 256) {
    float v;
    if (c < 512) {
      v = __cosf(erow[c] - cmacc[b * D + c] * (1.f / 1024.f));
    } else if (c < 1024) {
      int d = c - 512;
      v = (i < S - 1) ? __cosf(erow[D + d] - erow[d]) : 0.f;
    } else if (c < 1029) {
      v = msc[(size_t)idx * 5 + (c - 1024)];
    } else if (c == 1029) {
      int cnt = ((i < 8) ? i : 8) + ((S - 1 - i < 8) ? (S - 1 - i) : 8) + 1;
      v = semacc[i] / (4.f * (float)cnt * 512.f);
    } else if (c == 1030) {
      v = 1.f;
    } else v = 0.f;
    orow[c] = f2bf(v);
  }
}

// ---------------- bf16 MFMA GEMM: C[M,512] = A[M,K] @ BT[512,K]^T + bias ----------------
// tile 64x64, 4 waves, BK=32; A and BT both bf16 [*,K]; grid (M/64, 8) = 512 blocks
__global__ __launch_bounds__(256) void k_gemm(const u16* __restrict__ A,
    const u16* __restrict__ BT, float* __restrict__ C,
    const float* __restrict__ bias, int K) {
  __shared__ __align__(16) u16 sA[64 * 40];   // [m][k], stride 40 (80 B: 16B-aligned, 2-way banks)
  __shared__ __align__(16) u16 sB[64 * 40];   // [n][k]
  int tid = threadIdx.x, wave = tid >> 6, lane = tid & 63;
  int m0 = blockIdx.x * 64, n0 = blockIdx.y * 64;
  int lr = tid >> 2, lc = (tid & 3) * 8;
  int q8 = (lane >> 4) * 8, l15 = lane & 15;
  const u16* Ap = A + (size_t)(m0 + lr) * K + lc;
  const u16* Bp = BT + (size_t)(n0 + lr) * K + lc;
  f32x4 acc[4] = {};
  for (int k0 = 0; k0 < K; k0 += 32) {
    *(uint4*)&sA[lr * 40 + lc] = *(const uint4*)(Ap + k0);
    *(uint4*)&sB[lr * 40 + lc] = *(const uint4*)(Bp + k0);
    __syncthreads();
    bf16x8 af = *(const bf16x8*)&sA[(wave * 16 + l15) * 40 + q8];
#pragma unroll
    for (int f = 0; f < 4; ++f) {
      bf16x8 bfr = *(const bf16x8*)&sB[(f * 16 + l15) * 40 + q8];
      acc[f] = __builtin_amdgcn_mfma_f32_16x16x32_bf16(af, bfr, acc[f], 0, 0, 0);
    }
    __syncthreads();
  }
  int r0 = m0 + wave * 16 + (lane >> 4) * 4;
#pragma unroll
  for (int f = 0; f < 4; ++f) {
    int col = n0 + f * 16 + l15;
    float bv = bias ? bias[col] : 0.f;
#pragma unroll
    for (int r = 0; r < 4; ++r)
      C[(size_t)(r0 + r) * 512 + col] = acc[f][r] + bv;
  }
}

// ---------------- post-fuse: x = gelu(LN1(y1)); t = bf16(LN2(x)) ----------------
__global__ __launch_bounds__(256) void k_post_y1(const float* __restrict__ y,
    float* __restrict__ x, u16* __restrict__ t,
    const float* __restrict__ g1, const float* __restrict__ b1,
    const float* __restrict__ g2, const float* __restrict__ b2) {
  __shared__ float sm[8];
  int row = blockIdx.x, tid = threadIdx.x;
  size_t base = (size_t)row * 512;
  float v0 = y[base + tid], v1 = y[base + tid + 256];
  float s = v0 + v1, ss = v0 * v0 + v1 * v1;
  bred2(s, ss, sm, tid);
  float m = s * (1.f / 512.f);
  float inv = rsqrtf(ss * (1.f / 512.f) - m * m + 1e-5f);
  float x0 = gelu((v0 - m) * inv * g1[tid] + b1[tid]);
  float x1 = gelu((v1 - m) * inv * g1[tid + 256] + b1[tid + 256]);
  x[base + tid] = x0; x[base + tid + 256] = x1;
  s = x0 + x1; ss = x0 * x0 + x1 * x1;
  bred2(s, ss, sm, tid);
  m = s * (1.f / 512.f);
  inv = rsqrtf(ss * (1.f / 512.f) - m * m + 1e-5f);
  t[base + tid] = f2bf((x0 - m) * inv * g2[tid] + b2[tid]);
  t[base + tid + 256] = f2bf((x1 - m) * inv * g2[tid + 256] + b2[tid + 256]);
}

// ---------------- residual post: x += 0.1*gelu(h); then LN2->t (or LN3->out) ----------------
__global__ __launch_bounds__(256) void k_post_res(const float* __restrict__ h,
    float* __restrict__ x, u16* __restrict__ t, float* __restrict__ out,
    const float* __restrict__ g, const float* __restrict__ bb, int final_) {
  __shared__ float sm[8];
  int row = blockIdx.x, tid = threadIdx.x;
  size_t base = (size_t)row * 512;
  float x0 = x[base + tid] + 0.1f * gelu(h[base + tid]);
  float x1 = x[base + tid + 256] + 0.1f * gelu(h[base + tid + 256]);
  float s = x0 + x1, ss = x0 * x0 + x1 * x1;
  bred2(s, ss, sm, tid);
  float m = s * (1.f / 512.f);
  float inv = rsqrtf(ss * (1.f / 512.f) - m * m + 1e-5f);
  float n0 = (x0 - m) * inv * g[tid] + bb[tid];
  float n1 = (x1 - m) * inv * g[tid + 256] + bb[tid + 256];
  if (final_) {
    out[base + tid] = n0; out[base + tid + 256] = n1;
  } else {
    x[base + tid] = x0; x[base + tid + 256] = x1;
    t[base + tid] = f2bf(n0); t[base + tid + 256] = f2bf(n1);
  }
}

// ---------------------------------------------------------------------------
extern "C" void kernel_launch(void* const* d_in, const int* in_sizes, int n_in,
                              void* d_out, int out_size, void* d_ws, size_t ws_size,
                              hipStream_t stream) {
  const float* emb     = (const float*)d_in[0];
  const int*   tok     = (const int*)d_in[1];
  const float* mask    = (const float*)d_in[2];
  const float* sim     = (const float*)d_in[3];
  const float* W_scale = (const float*)d_in[4];
  const float* b_scale = (const float*)d_in[5];
  const float* W_sem   = (const float*)d_in[6];
  const float* b_sem   = (const float*)d_in[7];
  const float* W_ctx   = (const float*)d_in[8];
  const float* b_ctx   = (const float*)d_in[9];
  const float* W_fuse  = (const float*)d_in[10];
  const float* b_fuse  = (const float*)d_in[11];
  const float* ln1_g = (const float*)d_in[12], *ln1_b = (const float*)d_in[13];
  const float* ln2_g = (const float*)d_in[14], *ln2_b = (const float*)d_in[15];
  const float* ln3_g = (const float*)d_in[16], *ln3_b = (const float*)d_in[17];
  const float* W_e0 = (const float*)d_in[18], *b_e0 = (const float*)d_in[19];
  const float* W_e1 = (const float*)d_in[20], *b_e1 = (const float*)d_in[21];
  const float* W_e2 = (const float*)d_in[22], *b_e2 = (const float*)d_in[23];
  float* out = (float*)d_out;

  char* w = (char*)d_ws; size_t off = 0;
  auto alloc = [&](size_t bytes) { void* p = w + off; off += (bytes + 255) & ~(size_t)255; return p; };
  float* phases = (float*)alloc((size_t)4096 * 512 * 4);
  float* hbuf   = (float*)alloc((size_t)4096 * 512 * 4);
  float* xbuf   = (float*)alloc((size_t)4096 * 512 * 4);
  u16*   tbuf   = (u16*)  alloc((size_t)4096 * 512 * 2);
  u16*   xcat   = (u16*)  alloc((size_t)4096 * KCAT * 2);
  u16*   wcatT  = (u16*)  alloc((size_t)512 * KCAT * 2);
  u16*   We0T   = (u16*)  alloc((size_t)512 * 512 * 2);
  u16*   We1T   = (u16*)  alloc((size_t)512 * 512 * 2);
  u16*   We2T   = (u16*)  alloc((size_t)512 * 512 * 2);
  float* msc    = (float*)alloc((size_t)4096 * 5 * 4);
  // zero-init cluster (contiguous: one memset)
  float* semacc   = (float*)alloc((size_t)1024 * 4);          //   4 KB
  float* cmacc    = (float*)alloc((size_t)4 * 512 * 4);       //   8 KB
  float* dots_raw = (float*)alloc((size_t)4096 * 8 * 4);      // 128 KB
  float* normsq   = (float*)alloc((size_t)4096 * 4);          //  16 KB
  (void)ws_size; (void)in_sizes; (void)n_in; (void)out_size;

  hipMemsetAsync(semacc, 0, (1024 + 4 * 512 + 4096 * 8 + 4096) * 4, stream);

  k_phases<<<1024, 256, 0, stream>>>(emb, phases, 4096 * 512 / 4);
  k_cmean<<<32, 256, 0, stream>>>(emb, mask, cmacc);
  k_dots<<<dim3(64, 32), 256, 0, stream>>>(sim, tok, dots_raw, normsq);
  k_msc<<<1024, 256, 0, stream>>>(phases, msc);
  k_sem<<<1024, 256, 0, stream>>>(phases, dots_raw, normsq, semacc);

  k_prep<<<dim3(8, 8, 4), 256, 0, stream>>>(W_e0, W_e1, W_e2, W_fuse, We0T, We1T, We2T, wcatT);
  k_wcf<<<64, 256, 0, stream>>>(W_ctx, W_fuse, wcatT);
  k_wsmall<<<2, 256, 0, stream>>>(W_scale, W_sem, b_scale, b_sem, b_ctx, b_fuse, W_fuse, wcatT);

  k_xcat<<<4096, 256, 0, stream>>>(emb, cmacc, msc, semacc, xcat);
  k_gemm<<<dim3(64, 8), 256, 0, stream>>>(xcat, wcatT, hbuf, nullptr, KCAT);
  k_post_y1<<<4096, 256, 0, stream>>>(hbuf, xbuf, tbuf, ln1_g, ln1_b, ln2_g, ln2_b);

  k_gemm<<<dim3(64, 8), 256, 0, stream>>>(tbuf, We0T, hbuf, b_e0, 512);
  k_post_res<<<4096, 256, 0, stream>>>(hbuf, xbuf, tbuf, nullptr, ln2_g, ln2_b, 0);
  k_gemm<<<dim3(64, 8), 256, 0, stream>>>(tbuf, We1T, hbuf, b_e1, 512);
  k_post_res<<<4096, 256, 0, stream>>>(hbuf, xbuf, tbuf, nullptr, ln2_g, ln2_b, 0);
  k_gemm<<<dim3(64, 8), 256, 0, stream>>>(tbuf, We2T, hbuf, b_e2, 512);
  k_post_res<<<4096, 256, 0, stream>>>(hbuf, xbuf, nullptr, out, ln3_g, ln3_b, 1);
}

// Round 3
// 650.211 us; speedup vs baseline: 1.6509x; 1.3815x over previous
//
#include <hip/hip_runtime.h>

// ---------------------------------------------------------------------------
// HardwareOptimizedQuantumLLM  (B=4, S=1024, D=512, V=8192, SCALES={1,2,4,8,16}, WIN=8)
//
// R3: weight-fold stage parallelized (j-split + fp32 atomics). R2's k_wsmall
// ran 2 blocks / 512-deep latency chain = 165 us for 1.8 MFLOP.
// ---------------------------------------------------------------------------

#define DEV __device__ __forceinline__
typedef unsigned short u16;
typedef __bf16 bf16x8 __attribute__((ext_vector_type(8)));
typedef float f32x4 __attribute__((ext_vector_type(4)));

static constexpr int S = 1024;
static constexpr int D = 512;
static constexpr int KCAT = 1056;   // 512 ctx + 512 lc + 5 msc + 1 sem + 1 const + 25 pad

DEV u16 f2bf(float f) {            // fp32 -> bf16 (RNE)
  unsigned u = __float_as_uint(f);
  return (u16)((u + 0x7fffu + ((u >> 16) & 1u)) >> 16);
}
DEV float gelu(float x) { return 0.5f * x * (1.f + erff(x * 0.70710678118654752f)); }
DEV float wred(float v) {
#pragma unroll
  for (int off = 32; off; off >>= 1) v += __shfl_down(v, off, 64);
  return v;  // lane 0 holds the sum
}
DEV void bred2(float& a, float& b, float* sm, int tid) {  // 256-thread block reduce, 2 values
  a = wred(a); b = wred(b);
  int w = tid >> 6;
  if ((tid & 63) == 0) { sm[w] = a; sm[w + 4] = b; }
  __syncthreads();
  a = sm[0] + sm[1] + sm[2] + sm[3];
  b = sm[4] + sm[5] + sm[6] + sm[7];
  __syncthreads();
}

// ---------------- phases = tanh(emb) ----------------
__global__ __launch_bounds__(256) void k_phases(const float* __restrict__ emb,
                                                float* __restrict__ ph, int n4) {
  int idx = blockIdx.x * 256 + threadIdx.x, stride = gridDim.x * 256;
  for (; idx < n4; idx += stride) {
    float4 v = ((const float4*)emb)[idx];
    float4 o;
    o.x = tanhf(v.x); o.y = tanhf(v.y); o.z = tanhf(v.z); o.w = tanhf(v.w);
    ((float4*)ph)[idx] = o;
  }
}

// ---------------- context mean accumulation (grid: B*8) ----------------
__global__ __launch_bounds__(256) void k_cmean(const float* __restrict__ emb,
                                               const float* __restrict__ mask,
                                               float* __restrict__ cmacc) {
  int b = blockIdx.x >> 3, chunk = blockIdx.x & 7, tid = threadIdx.x;
  float a0 = 0.f, a1 = 0.f;
  for (int s = chunk * 128; s < chunk * 128 + 128; ++s) {
    float m = mask[b * S + s];
    const float* row = emb + (size_t)(b * S + s) * D;
    a0 += row[tid] * m; a1 += row[tid + 256] * m;
  }
  atomicAdd(cmacc + b * D + tid, a0);
  atomicAdd(cmacc + b * D + tid + 256, a1);
}

// ---------------- banded tsim + norms, chunk-parallel band staging ----------------
// grid.x = B*16 (64-anchor position groups), grid.y = 32 (256-float V chunks)
// LDS sT[c][row]: 256 x 76(pad, 72 rows used) fp32 = 76 KB -> 2 blocks/CU.
static constexpr int DP = 76;
__global__ __launch_bounds__(256) void k_dots(const float* __restrict__ sim,
                                              const int* __restrict__ tok,
                                              float* __restrict__ dots_raw,
                                              float* __restrict__ normsq) {
  __shared__ float sT[256 * DP];
  __shared__ int stok[72];
  int bx = blockIdx.x, cy = blockIdx.y, tid = threadIdx.x;
  int b = bx >> 4, g0 = (bx & 15) * 64;
  int gidx = b * S + g0;
  if (tid < 72) {
    int p = g0 + tid;
    stok[tid] = (p < S) ? tok[b * S + p] : -1;
  }
  __syncthreads();
  int c = tid, cbase = cy * 256;
#pragma unroll 3
  for (int it = 0; it < 18; ++it) {
    float4 v;
#pragma unroll
    for (int j = 0; j < 4; ++j) {
      int tk = stok[it * 4 + j];
      ((float*)&v)[j] = (tk >= 0) ? sim[(size_t)tk * 8192 + cbase + c] : 0.f;
    }
    *(float4*)&sT[c * DP + it * 4] = v;
  }
  __syncthreads();
  int wave = tid >> 6, lane = tid & 63;
  float acc[9] = {};
#pragma unroll 2
  for (int cc = 0; cc < 64; ++cc) {
    const float* row = &sT[(wave * 64 + cc) * DP];
    float va = row[lane];
    acc[8] += va * va;
#pragma unroll
    for (int o = 1; o <= 8; ++o) acc[o - 1] += va * row[lane + o];
  }
  __syncthreads();
  float* red = sT;
#pragma unroll
  for (int s = 0; s < 9; ++s) red[(wave * 9 + s) * 64 + lane] = acc[s];
  __syncthreads();
  for (int u = tid; u < 576; u += 256) {
    int s = u >> 6, a = u & 63;
    float v = red[s * 64 + a] + red[(9 + s) * 64 + a] +
              red[(18 + s) * 64 + a] + red[(27 + s) * 64 + a];
    if (s < 8) atomicAdd(&dots_raw[(size_t)(gidx + a) * 8 + s], v);
    else       atomicAdd(&normsq[gidx + a], v);
  }
}

// ---------------- multi-scale coherence msc (one wave per (b,i)) ----------------
__global__ __launch_bounds__(256) void k_msc(const float* __restrict__ ph,
                                             float* __restrict__ msc) {
  int wave = threadIdx.x >> 6, lane = threadIdx.x & 63;
  int idx = blockIdx.x * 4 + wave, i = idx & 1023;
  const float* base = ph + (size_t)idx * D;
  int jmax = (S - 1 - i < 15) ? (S - 1 - i) : 15;
  float a0 = 0.f, a1 = 0.f, a2 = 0.f, a3 = 0.f, a4 = 0.f;
  for (int it = 0; it < 8; ++it) {
    int d = lane + it * 64;
    float sp = 0.f, sc = 0.f, ss = 0.f;
#pragma unroll
    for (int j = 0; j < 16; ++j) {
      float p = (j <= jmax) ? base[(size_t)j * D + d] : 0.f;
      sp += p; sc += __cosf(p); ss += __sinf(p);
      if (j == 0) a0 += __cosf(sp) * sc + __sinf(sp) * ss;
      else if (j == 1)  { float wm = sp * 0.5f;    a1 += __cosf(wm) * (sc * 0.5f)    + __sinf(wm) * (ss * 0.5f); }
      else if (j == 3)  { float wm = sp * 0.25f;   a2 += __cosf(wm) * (sc * 0.25f)   + __sinf(wm) * (ss * 0.25f); }
      else if (j == 7)  { float wm = sp * 0.125f;  a3 += __cosf(wm) * (sc * 0.125f)  + __sinf(wm) * (ss * 0.125f); }
      else if (j == 15) { float wm = sp * 0.0625f; a4 += __cosf(wm) * (sc * 0.0625f) + __sinf(wm) * (ss * 0.0625f); }
    }
  }
  a0 = wred(a0); a1 = wred(a1); a2 = wred(a2); a3 = wred(a3); a4 = wred(a4);
  if (lane == 0) {
    float* o = msc + (size_t)idx * 5;
    o[0] = a0 * (1.f / 512.f);
    o[1] = (jmax >= 1)  ? a1 * (1.f / 512.f) : 0.f;
    o[2] = (jmax >= 3)  ? a2 * (1.f / 512.f) : 0.f;
    o[3] = (jmax >= 7)  ? a3 * (1.f / 512.f) : 0.f;
    o[4] = (jmax >= 15) ? a4 * (1.f / 512.f) : 0.f;
  }
}

// ---------------- semantic coherence (one wave per (b,i)); scratch-free ----------------
__global__ __launch_bounds__(256) void k_sem(const float* __restrict__ ph,
                                             const float* __restrict__ dots_raw,
                                             const float* __restrict__ normsq,
                                             float* __restrict__ semacc) {
  __shared__ float sw[4][17];
  int wave = threadIdx.x >> 6, lane = threadIdx.x & 63;
  int idx = blockIdx.x * 4 + wave, i = idx & 1023;
  if (lane < 17) {
    int o = lane - 8, j = i + o;
    float v = 0.f;
    if (j >= 0 && j < S) {
      if (o == 0) v = 1.f;
      else {
        float dr = (o > 0) ? dots_raw[(size_t)idx * 8 + o - 1]
                           : dots_raw[(size_t)(idx + o) * 8 + (-o - 1)];
        float ni = fmaxf(sqrtf(normsq[idx]), 1e-12f);
        float nj = fmaxf(sqrtf(normsq[idx + o]), 1e-12f);
        v = dr / (ni * nj);
      }
    }
    sw[wave][lane] = v;
  }
  __syncthreads();
  const float* pbase = ph + (size_t)idx * D;
  float acc = 0.f;
  for (int it = 0; it < 8; ++it) {
    int d = lane + it * 64;
    float p0 = pbase[d];
#pragma unroll
    for (int oi = 0; oi < 17; ++oi) {
      int o = oi - 8, j = i + o;
      bool valid = (j >= 0) && (j < S);
      int oc = valid ? o : 0;
      float pj = ph[(size_t)(idx + oc) * D + d];
      float sv = sw[wave][oi];
      acc += valid ? __cosf((p0 - pj) * sv) : 0.f;
    }
  }
  acc = wred(acc);
  if (lane == 0) atomicAdd(semacc + i, acc);
}

// ---------------- weight prep: fp32 [k][n] -> bf16 [n][k] (grid 8,8,4) ----------------
__global__ __launch_bounds__(256) void k_prep(const float* __restrict__ W0,
    const float* __restrict__ W1, const float* __restrict__ W2,
    const float* __restrict__ Wf, u16* __restrict__ T0, u16* __restrict__ T1,
    u16* __restrict__ T2, u16* __restrict__ wcatT) {
  __shared__ float tile[64][65];
  int z = blockIdx.z;
  const float* src = z == 0 ? W0 : z == 1 ? W1 : z == 2 ? W2 : Wf + (size_t)1536 * 512;
  int r0 = blockIdx.y * 64, c0 = blockIdx.x * 64;
  int tr = threadIdx.x >> 6, tc = threadIdx.x & 63;
#pragma unroll 4
  for (int i = 0; i < 16; ++i)
    tile[tr + i * 4][tc] = src[(size_t)(r0 + tr + i * 4) * 512 + c0 + tc];
  __syncthreads();
#pragma unroll 4
  for (int i = 0; i < 16; ++i) {
    int n = c0 + tr + i * 4, k = r0 + tc;
    u16 v = f2bf(tile[tc][tr + i * 4]);
    if (z == 3) wcatT[(size_t)n * KCAT + 512 + k] = v;
    else (z == 0 ? T0 : z == 1 ? T1 : T2)[(size_t)n * 512 + k] = v;
  }
}

// ---------------- ctx fold: ctx_acc[k][n] += sum_j W_ctx[k][j]*Wf3[j][n] ----------------
// grid (64, 4): bx = (kgroup<<1)|nhalf, by = j-chunk of 128. fp32 atomics.
__global__ __launch_bounds__(256) void k_wcf(const float* __restrict__ wctx,
                                             const float* __restrict__ wfuse,
                                             float* __restrict__ ctx_acc) {
  int n = (blockIdx.x & 1) * 256 + threadIdx.x;
  int kbase = (blockIdx.x >> 1) * 16;
  int j0 = blockIdx.y * 128;
  float acc[16] = {};
  for (int j = j0; j < j0 + 128; ++j) {
    float wf3 = wfuse[(size_t)(1024 + j) * 512 + n];
#pragma unroll
    for (int kk = 0; kk < 16; ++kk) acc[kk] += wctx[(size_t)(kbase + kk) * 512 + j] * wf3;
  }
#pragma unroll
  for (int kk = 0; kk < 16; ++kk)
    atomicAdd(&ctx_acc[(size_t)(kbase + kk) * 512 + n], acc[kk]);
}

// ---------------- pack ctx_acc fp32 [k][n] -> wcatT bf16 [n][k0..511] (grid 8,8) ----------------
__global__ __launch_bounds__(256) void k_pack(const float* __restrict__ src,
                                              u16* __restrict__ wcatT) {
  __shared__ float tile[64][65];
  int r0 = blockIdx.y * 64, c0 = blockIdx.x * 64;   // r=k, c=n
  int tr = threadIdx.x >> 6, tc = threadIdx.x & 63;
#pragma unroll 4
  for (int i = 0; i < 16; ++i)
    tile[tr + i * 4][tc] = src[(size_t)(r0 + tr + i * 4) * 512 + c0 + tc];
  __syncthreads();
#pragma unroll 4
  for (int i = 0; i < 16; ++i)
    wcatT[(size_t)(c0 + tr + i * 4) * KCAT + r0 + tc] = f2bf(tile[tc][tr + i * 4]);
}

// ---------------- small folds: sm_acc[7][512] += partials (grid 2 x 32) ----------------
__global__ __launch_bounds__(256) void k_wsmall(const float* __restrict__ Wsc,
    const float* __restrict__ Wsm, const float* __restrict__ bsc,
    const float* __restrict__ bsm, const float* __restrict__ bcx,
    const float* __restrict__ Wf, float* __restrict__ sm_acc) {
  int n = blockIdx.x * 256 + threadIdx.x;
  int j0 = blockIdx.y * 16;
  float a0 = 0.f, a1 = 0.f, a2 = 0.f, a3 = 0.f, a4 = 0.f, au = 0.f, ac = 0.f;
  for (int j = j0; j < j0 + 16; ++j) {
    float wf1 = Wf[(size_t)j * 512 + n];
    float wf2 = Wf[(size_t)(512 + j) * 512 + n];
    float wf3 = Wf[(size_t)(1024 + j) * 512 + n];
    a0 += Wsc[j] * wf1; a1 += Wsc[512 + j] * wf1; a2 += Wsc[1024 + j] * wf1;
    a3 += Wsc[1536 + j] * wf1; a4 += Wsc[2048 + j] * wf1;
    au += Wsm[j] * wf2;
    ac += bsc[j] * wf1 + bsm[j] * wf2 + bcx[j] * wf3;
  }
  atomicAdd(&sm_acc[0 * 512 + n], a0);
  atomicAdd(&sm_acc[1 * 512 + n], a1);
  atomicAdd(&sm_acc[2 * 512 + n], a2);
  atomicAdd(&sm_acc[3 * 512 + n], a3);
  atomicAdd(&sm_acc[4 * 512 + n], a4);
  atomicAdd(&sm_acc[5 * 512 + n], au);
  atomicAdd(&sm_acc[6 * 512 + n], ac);
}

// ---------------- finalize wcatT cols 1024..1055 (grid 2) ----------------
__global__ __launch_bounds__(256) void k_wfin(const float* __restrict__ sm_acc,
    const float* __restrict__ bfu, u16* __restrict__ wcatT) {
  int n = blockIdx.x * 256 + threadIdx.x;
  u16* row = wcatT + (size_t)n * KCAT;
#pragma unroll
  for (int s = 0; s < 6; ++s) row[1024 + s] = f2bf(sm_acc[s * 512 + n]);
  row[1030] = f2bf(sm_acc[6 * 512 + n] + bfu[n]);
  for (int k = 1031; k < KCAT; ++k) row[k] = 0;
}

// ---------------- build Xcat (bf16): [cos(emb-cmean) | lc | msc | sem | 1 | 0] ----------------
__global__ __launch_bounds__(256) void k_xcat(const float* __restrict__ emb,
    const float* __restrict__ cmacc, const float* __restrict__ msc,
    const float* __restrict__ semacc, u16* __restrict__ xcat) {
  int idx = blockIdx.x, b = idx >> 10, i = idx & 1023, tid = threadIdx.x;
  const float* erow = emb + (size_t)idx * D;
  u16* orow = xcat + (size_t)idx * KCAT;
  for (int c = tid; c < KCAT; c += 256) {
    float v;
    if (c < 512) {
      v = __cosf(erow[c] - cmacc[b * D + c] * (1.f / 1024.f));
    } else if (c < 1024) {
      int d = c - 512;
      v = (i < S - 1) ? __cosf(erow[D + d] - erow[d]) : 0.f;
    } else if (c < 1029) {
      v = msc[(size_t)idx * 5 + (c - 1024)];
    } else if (c == 1029) {
      int cnt = ((i < 8) ? i : 8) + ((S - 1 - i < 8) ? (S - 1 - i) : 8) + 1;
      v = semacc[i] / (4.f * (float)cnt * 512.f);
    } else if (c == 1030) {
      v = 1.f;
    } else v = 0.f;
    orow[c] = f2bf(v);
  }
}

// ---------------- bf16 MFMA GEMM: C[M,512] = A[M,K] @ BT[512,K]^T + bias ----------------
__global__ __launch_bounds__(256) void k_gemm(const u16* __restrict__ A,
    const u16* __restrict__ BT, float* __restrict__ C,
    const float* __restrict__ bias, int K) {
  __shared__ __align__(16) u16 sA[64 * 40];
  __shared__ __align__(16) u16 sB[64 * 40];
  int tid = threadIdx.x, wave = tid >> 6, lane = tid & 63;
  int m0 = blockIdx.x * 64, n0 = blockIdx.y * 64;
  int lr = tid >> 2, lc = (tid & 3) * 8;
  int q8 = (lane >> 4) * 8, l15 = lane & 15;
  const u16* Ap = A + (size_t)(m0 + lr) * K + lc;
  const u16* Bp = BT + (size_t)(n0 + lr) * K + lc;
  f32x4 acc[4] = {};
  for (int k0 = 0; k0 < K; k0 += 32) {
    *(uint4*)&sA[lr * 40 + lc] = *(const uint4*)(Ap + k0);
    *(uint4*)&sB[lr * 40 + lc] = *(const uint4*)(Bp + k0);
    __syncthreads();
    bf16x8 af = *(const bf16x8*)&sA[(wave * 16 + l15) * 40 + q8];
#pragma unroll
    for (int f = 0; f < 4; ++f) {
      bf16x8 bfr = *(const bf16x8*)&sB[(f * 16 + l15) * 40 + q8];
      acc[f] = __builtin_amdgcn_mfma_f32_16x16x32_bf16(af, bfr, acc[f], 0, 0, 0);
    }
    __syncthreads();
  }
  int r0 = m0 + wave * 16 + (lane >> 4) * 4;
#pragma unroll
  for (int f = 0; f < 4; ++f) {
    int col = n0 + f * 16 + l15;
    float bv = bias ? bias[col] : 0.f;
#pragma unroll
    for (int r = 0; r < 4; ++r)
      C[(size_t)(r0 + r) * 512 + col] = acc[f][r] + bv;
  }
}

// ---------------- post-fuse: x = gelu(LN1(y1)); t = bf16(LN2(x)) ----------------
__global__ __launch_bounds__(256) void k_post_y1(const float* __restrict__ y,
    float* __restrict__ x, u16* __restrict__ t,
    const float* __restrict__ g1, const float* __restrict__ b1,
    const float* __restrict__ g2, const float* __restrict__ b2) {
  __shared__ float sm[8];
  int row = blockIdx.x, tid = threadIdx.x;
  size_t base = (size_t)row * 512;
  float v0 = y[base + tid], v1 = y[base + tid + 256];
  float s = v0 + v1, ss = v0 * v0 + v1 * v1;
  bred2(s, ss, sm, tid);
  float m = s * (1.f / 512.f);
  float inv = rsqrtf(ss * (1.f / 512.f) - m * m + 1e-5f);
  float x0 = gelu((v0 - m) * inv * g1[tid] + b1[tid]);
  float x1 = gelu((v1 - m) * inv * g1[tid + 256] + b1[tid + 256]);
  x[base + tid] = x0; x[base + tid + 256] = x1;
  s = x0 + x1; ss = x0 * x0 + x1 * x1;
  bred2(s, ss, sm, tid);
  m = s * (1.f / 512.f);
  inv = rsqrtf(ss * (1.f / 512.f) - m * m + 1e-5f);
  t[base + tid] = f2bf((x0 - m) * inv * g2[tid] + b2[tid]);
  t[base + tid + 256] = f2bf((x1 - m) * inv * g2[tid + 256] + b2[tid + 256]);
}

// ---------------- residual post: x += 0.1*gelu(h); then LN2->t (or LN3->out) ----------------
__global__ __launch_bounds__(256) void k_post_res(const float* __restrict__ h,
    float* __restrict__ x, u16* __restrict__ t, float* __restrict__ out,
    const float* __restrict__ g, const float* __restrict__ bb, int final_) {
  __shared__ float sm[8];
  int row = blockIdx.x, tid = threadIdx.x;
  size_t base = (size_t)row * 512;
  float x0 = x[base + tid] + 0.1f * gelu(h[base + tid]);
  float x1 = x[base + tid + 256] + 0.1f * gelu(h[base + tid + 256]);
  float s = x0 + x1, ss = x0 * x0 + x1 * x1;
  bred2(s, ss, sm, tid);
  float m = s * (1.f / 512.f);
  float inv = rsqrtf(ss * (1.f / 512.f) - m * m + 1e-5f);
  float n0 = (x0 - m) * inv * g[tid] + bb[tid];
  float n1 = (x1 - m) * inv * g[tid + 256] + bb[tid + 256];
  if (final_) {
    out[base + tid] = n0; out[base + tid + 256] = n1;
  } else {
    x[base + tid] = x0; x[base + tid + 256] = x1;
    t[base + tid] = f2bf(n0); t[base + tid + 256] = f2bf(n1);
  }
}

// ---------------------------------------------------------------------------
extern "C" void kernel_launch(void* const* d_in, const int* in_sizes, int n_in,
                              void* d_out, int out_size, void* d_ws, size_t ws_size,
                              hipStream_t stream) {
  const float* emb     = (const float*)d_in[0];
  const int*   tok     = (const int*)d_in[1];
  const float* mask    = (const float*)d_in[2];
  const float* sim     = (const float*)d_in[3];
  const float* W_scale = (const float*)d_in[4];
  const float* b_scale = (const float*)d_in[5];
  const float* W_sem   = (const float*)d_in[6];
  const float* b_sem   = (const float*)d_in[7];
  const float* W_ctx   = (const float*)d_in[8];
  const float* b_ctx   = (const float*)d_in[9];
  const float* W_fuse  = (const float*)d_in[10];
  const float* b_fuse  = (const float*)d_in[11];
  const float* ln1_g = (const float*)d_in[12], *ln1_b = (const float*)d_in[13];
  const float* ln2_g = (const float*)d_in[14], *ln2_b = (const float*)d_in[15];
  const float* ln3_g = (const float*)d_in[16], *ln3_b = (const float*)d_in[17];
  const float* W_e0 = (const float*)d_in[18], *b_e0 = (const float*)d_in[19];
  const float* W_e1 = (const float*)d_in[20], *b_e1 = (const float*)d_in[21];
  const float* W_e2 = (const float*)d_in[22], *b_e2 = (const float*)d_in[23];
  float* out = (float*)d_out;

  char* w = (char*)d_ws; size_t off = 0;
  auto alloc = [&](size_t bytes) { void* p = w + off; off += (bytes + 255) & ~(size_t)255; return p; };
  float* phases = (float*)alloc((size_t)4096 * 512 * 4);
  float* hbuf   = (float*)alloc((size_t)4096 * 512 * 4);
  float* xbuf   = (float*)alloc((size_t)4096 * 512 * 4);
  u16*   tbuf   = (u16*)  alloc((size_t)4096 * 512 * 2);
  u16*   xcat   = (u16*)  alloc((size_t)4096 * KCAT * 2);
  u16*   wcatT  = (u16*)  alloc((size_t)512 * KCAT * 2);
  u16*   We0T   = (u16*)  alloc((size_t)512 * 512 * 2);
  u16*   We1T   = (u16*)  alloc((size_t)512 * 512 * 2);
  u16*   We2T   = (u16*)  alloc((size_t)512 * 512 * 2);
  float* msc    = (float*)alloc((size_t)4096 * 5 * 4);
  // zero-init cluster (contiguous, sizes all multiples of 256 B: one memset)
  float* semacc   = (float*)alloc((size_t)1024 * 4);          //   4 KB
  float* cmacc    = (float*)alloc((size_t)4 * 512 * 4);       //   8 KB
  float* dots_raw = (float*)alloc((size_t)4096 * 8 * 4);      // 128 KB
  float* normsq   = (float*)alloc((size_t)4096 * 4);          //  16 KB
  float* ctx_acc  = (float*)alloc((size_t)512 * 512 * 4);     //   1 MB
  float* sm_acc   = (float*)alloc((size_t)7 * 512 * 4);       //  14 KB
  (void)ws_size; (void)in_sizes; (void)n_in; (void)out_size;

  size_t zbytes = (size_t)(1024 + 4 * 512 + 4096 * 8 + 4096 + 512 * 512 + 7 * 512) * 4;
  hipMemsetAsync(semacc, 0, zbytes, stream);

  k_phases<<<1024, 256, 0, stream>>>(emb, phases, 4096 * 512 / 4);
  k_cmean<<<32, 256, 0, stream>>>(emb, mask, cmacc);
  k_dots<<<dim3(64, 32), 256, 0, stream>>>(sim, tok, dots_raw, normsq);
  k_msc<<<1024, 256, 0, stream>>>(phases, msc);
  k_sem<<<1024, 256, 0, stream>>>(phases, dots_raw, normsq, semacc);

  k_prep<<<dim3(8, 8, 4), 256, 0, stream>>>(W_e0, W_e1, W_e2, W_fuse, We0T, We1T, We2T, wcatT);
  k_wcf<<<dim3(64, 4), 256, 0, stream>>>(W_ctx, W_fuse, ctx_acc);
  k_pack<<<dim3(8, 8), 256, 0, stream>>>(ctx_acc, wcatT);
  k_wsmall<<<dim3(2, 32), 256, 0, stream>>>(W_scale, W_sem, b_scale, b_sem, b_ctx, W_fuse, sm_acc);
  k_wfin<<<2, 256, 0, stream>>>(sm_acc, b_fuse, wcatT);

  k_xcat<<<4096, 256, 0, stream>>>(emb, cmacc, msc, semacc, xcat);
  k_gemm<<<dim3(64, 8), 256, 0, stream>>>(xcat, wcatT, hbuf, nullptr, KCAT);
  k_post_y1<<<4096, 256, 0, stream>>>(hbuf, xbuf, tbuf, ln1_g, ln1_b, ln2_g, ln2_b);

  k_gemm<<<dim3(64, 8), 256, 0, stream>>>(tbuf, We0T, hbuf, b_e0, 512);
  k_post_res<<<4096, 256, 0, stream>>>(hbuf, xbuf, tbuf, nullptr, ln2_g, ln2_b, 0);
  k_gemm<<<dim3(64, 8), 256, 0, stream>>>(tbuf, We1T, hbuf, b_e1, 512);
  k_post_res<<<4096, 256, 0, stream>>>(hbuf, xbuf, tbuf, nullptr, ln2_g, ln2_b, 0);
  k_gemm<<<dim3(64, 8), 256, 0, stream>>>(tbuf, We2T, hbuf, b_e2, 512);
  k_post_res<<<4096, 256, 0, stream>>>(hbuf, xbuf, nullptr, out, ln3_g, ln3_b, 1);
}